// Round 1
// baseline (5034.644 us; speedup 1.0000x reference)
//
#include <hip/hip_runtime.h>
#include <hip/hip_bf16.h>
#include <math.h>

#define Bdim 128
#define Tdim 96
#define Fdim 64
#define Sdim 16
#define Rdim 6
#define KACT 4
#define Hdim 128
#define DK 64
#define DV 128
#define HC 4
#define CK 32
#define CV 32

__device__ __forceinline__ float sigmoidf_(float x) { return 1.0f / (1.0f + expf(-x)); }

// ---------------- Kernel 1: precompute gamma_h, k, v for all (b,t) ----------------
__global__ __launch_bounds__(128) void k_pre(
    const float* __restrict__ x, const float* __restrict__ mask,
    const float* __restrict__ delta, const float* __restrict__ xlast,
    const float* __restrict__ xmean,
    const float* __restrict__ Wgx, const float* __restrict__ bgx,
    const float* __restrict__ Wgh, const float* __restrict__ bgh,
    const float* __restrict__ Wk, const float* __restrict__ bk,
    const float* __restrict__ Wv, const float* __restrict__ bv,
    float* __restrict__ ghO, float* __restrict__ kO, float* __restrict__ vO)
{
    const int bt = blockIdx.x;
    const int b = bt / Tdim, t = bt % Tdim;
    const int tid = threadIdx.x;
    __shared__ float d_s[Fdim], xh_s[Fdim];
    const int base = (b * Tdim + t) * Fdim;

    if (tid < Fdim) d_s[tid] = delta[base + tid];
    __syncthreads();

    if (tid < Fdim) {
        float z = bgx[tid];
        #pragma unroll 8
        for (int i = 0; i < Fdim; ++i) z += d_s[i] * Wgx[i * Fdim + tid];
        float gx = expf(-fmaxf(z, 0.0f));
        float m = mask[base + tid], xv = x[base + tid];
        float xl = xlast[base + tid], xm = xmean[b * Fdim + tid];
        xh_s[tid] = m * xv + (1.0f - m) * (gx * xl + (1.0f - gx) * xm);
    }
    {   // gamma_h: 128 outputs, all threads
        float z = bgh[tid];
        #pragma unroll 8
        for (int i = 0; i < Fdim; ++i) z += d_s[i] * Wgh[i * Hdim + tid];
        ghO[(b * Tdim + t) * Hdim + tid] = expf(-fmaxf(z, 0.0f));
    }
    __syncthreads();

    if (tid < DK) {
        float z = bk[tid];
        #pragma unroll 8
        for (int j = 0; j < Fdim; ++j) z += xh_s[j] * Wk[j * DK + tid];
        kO[(b * Tdim + t) * DK + tid] = z;
    }
    {
        float z = bv[tid];
        #pragma unroll 8
        for (int j = 0; j < Fdim; ++j) z += xh_s[j] * Wv[j * DV + tid];
        vO[(b * Tdim + t) * DV + tid] = z;
    }
}

// ---------------- Kernel 2: the sequential scan, one block per batch element ----------------
__global__ __launch_bounds__(768) void k_seq(
    const float* __restrict__ statics,
    const float* __restrict__ h0, const float* __restrict__ c0,
    const float* __restrict__ bk_in, const float* __restrict__ bv_in,
    const float* __restrict__ Wq_in,
    const float* __restrict__ Wx_rnn, const float* __restrict__ Wh_rnn,
    const float* __restrict__ b_rnn,
    const float* __restrict__ Wq_c, const float* __restrict__ Wk_c,
    const float* __restrict__ Wv_c, const float* __restrict__ Wout_c,
    const float* __restrict__ W1, const float* __restrict__ b1,
    const float* __restrict__ W2, const float* __restrict__ b2,
    const float* __restrict__ ghG, const float* __restrict__ kG, const float* __restrict__ vG,
    float* __restrict__ out)
{
    const int b = blockIdx.x;
    const int tid = threadIdx.x;
    const int wave = tid >> 6, lane = tid & 63;

    __shared__ float hs[Rdim][Hdim], cs[Rdim][Hdim], hn[Rdim][Hdim], cn[Rdim][Hdim];
    __shared__ float rim[Rdim][DV];
    __shared__ float pre_s[Rdim][4 * Hdim];
    __shared__ float qc[Rdim][Hdim], kc[Rdim][Hdim], vc[Rdim][Hdim], ctx_s[Rdim][Hdim];
    __shared__ float gh_s[Hdim], kk[DK], vv[DV], bk_s[DK], bv_s[DV];
    __shared__ float s0[Rdim], s1[Rdim], p0[Rdim], p1[Rdim], mk[Rdim];
    __shared__ float scs[HC][Rdim][Rdim], cps[HC][Rdim][Rdim];

    // init carry
    {
        int r = tid >> 7, j = tid & 127;
        hs[r][j] = h0[b * Rdim * Hdim + tid];
        cs[r][j] = c0[b * Rdim * Hdim + tid];
    }
    if (tid < DK) bk_s[tid] = bk_in[tid];
    if (tid < DV) bv_s[tid] = bv_in[tid];
    __syncthreads();

    for (int t = 0; t < Tdim; ++t) {
        // A1: load per-step precomputed vectors
        if (tid < Hdim) {
            gh_s[tid] = ghG[(b * Tdim + t) * Hdim + tid];
            vv[tid]   = vG [(b * Tdim + t) * DV   + tid];
        }
        if (tid < DK) kk[tid] = kG[(b * Tdim + t) * DK + tid];
        __syncthreads();

        // A2: decay hs (h_old == decayed hs; inactive rows simply keep it)
        {
            int r = tid >> 7, j = tid & 127;
            hs[r][j] *= gh_s[j];
        }
        __syncthreads();

        // B: q = hs @ Wq_in[r]; s0/s1 via in-wave reduction (wave r handles unit r)
        if (wave < Rdim) {
            const int r = wave, c = lane;
            const float* wq = Wq_in + r * Hdim * DK + c;
            float qv = 0.0f;
            #pragma unroll 8
            for (int h = 0; h < Hdim; ++h) qv += hs[r][h] * wq[h * DK];
            float a0 = qv * kk[c];
            float a1 = qv * bk_s[c];
            #pragma unroll
            for (int off = 32; off > 0; off >>= 1) {
                a0 += __shfl_xor(a0, off);
                a1 += __shfl_xor(a1, off);
            }
            if (lane == 0) { s0[r] = a0 * 0.125f; s1[r] = a1 * 0.125f; }
        }
        __syncthreads();

        // C: 2-way softmax probs + top-KACT mask (stable tie-break like jax top_k)
        if (tid < Rdim) {
            float m = fmaxf(s0[tid], s1[tid]);
            float e0 = expf(s0[tid] - m), e1 = expf(s1[tid] - m);
            float inv = 1.0f / (e0 + e1);
            p0[tid] = e0 * inv; p1[tid] = e1 * inv;
            int rank = 0;
            #pragma unroll
            for (int j = 0; j < Rdim; ++j)
                rank += (s0[j] > s0[tid] || (s0[j] == s0[tid] && j < tid)) ? 1 : 0;
            mk[tid] = (rank < KACT) ? 1.0f : 0.0f;
        }
        __syncthreads();

        // D: rim_in = p0*v + p1*bv
        {
            int r = tid >> 7, j = tid & 127;
            rim[r][j] = p0[r] * vv[j] + p1[r] * bv_s[j];
        }
        __syncthreads();

        // E: pre = rim@Wx + hs@Wh + b (the big one); float4 over output cols
        {
            int r = tid >> 7, e4 = tid & 127;
            int c0i = e4 * 4;
            const float4* wx = (const float4*)(Wx_rnn + (r * Hdim) * 512 + c0i);
            const float4* wh = (const float4*)(Wh_rnn + (r * Hdim) * 512 + c0i);
            float4 acc = *(const float4*)(b_rnn + r * 512 + c0i);
            #pragma unroll 4
            for (int d = 0; d < Hdim; ++d) {
                float rd = rim[r][d], hd = hs[r][d];
                float4 a = wx[d * 128];
                float4 w = wh[d * 128];
                acc.x += rd * a.x + hd * w.x;
                acc.y += rd * a.y + hd * w.y;
                acc.z += rd * a.z + hd * w.z;
                acc.w += rd * a.w + hd * w.w;
            }
            *(float4*)&pre_s[r][c0i] = acc;
        }
        __syncthreads();

        // F: LSTM elementwise
        {
            int r = tid >> 7, j = tid & 127;
            float ig = pre_s[r][j];
            float fg = pre_s[r][Hdim + j];
            float gg = pre_s[r][2 * Hdim + j];
            float og = pre_s[r][3 * Hdim + j];
            float cnew = sigmoidf_(fg) * cs[r][j] + sigmoidf_(ig) * tanhf(gg);
            float hnew = sigmoidf_(og) * tanhf(cnew);
            cn[r][j] = cnew;
            hn[r][j] = hnew;   // h_b == h_new in forward pass
        }
        __syncthreads();

        // G: qc/kc/vc = hn @ {Wq_c,Wk_c,Wv_c}[r]; float4 over output cols
        if (tid < 576) {
            int r = tid / 96, e4 = tid % 96;
            int col = e4 * 4, matid = col >> 7, cc = col & 127;
            const float* Wm = (matid == 0 ? Wq_c : (matid == 1 ? Wk_c : Wv_c))
                              + (r * Hdim) * Hdim + cc;
            float4 acc = make_float4(0.f, 0.f, 0.f, 0.f);
            #pragma unroll 4
            for (int d = 0; d < Hdim; ++d) {
                float hd = hn[r][d];
                float4 w = *(const float4*)(Wm + d * Hdim);
                acc.x += hd * w.x; acc.y += hd * w.y;
                acc.z += hd * w.z; acc.w += hd * w.w;
            }
            float* dst = (matid == 0 ? &qc[r][cc] : (matid == 1 ? &kc[r][cc] : &vc[r][cc]));
            *(float4*)dst = acc;
        }
        __syncthreads();

        // H: attention scores over units (per head)
        if (tid < HC * Rdim * Rdim) {
            int h = tid / (Rdim * Rdim), rr = (tid / Rdim) % Rdim, ss = tid % Rdim;
            float acc = 0.0f;
            #pragma unroll 8
            for (int d = 0; d < CK; ++d) acc += qc[rr][h * CK + d] * kc[ss][h * CK + d];
            scs[h][rr][ss] = acc * 0.17677669529663687f;  // 1/sqrt(32)
        }
        __syncthreads();

        // I: softmax over s, times activation mask on r
        if (tid < HC * Rdim) {
            int h = tid / Rdim, rr = tid % Rdim;
            float m = scs[h][rr][0];
            #pragma unroll
            for (int ss = 1; ss < Rdim; ++ss) m = fmaxf(m, scs[h][rr][ss]);
            float e[Rdim], sum = 0.0f;
            #pragma unroll
            for (int ss = 0; ss < Rdim; ++ss) { e[ss] = expf(scs[h][rr][ss] - m); sum += e[ss]; }
            float inv = mk[rr] / sum;
            #pragma unroll
            for (int ss = 0; ss < Rdim; ++ss) cps[h][rr][ss] = e[ss] * inv;
        }
        __syncthreads();

        // J: ctx = cprobs @ vc
        {
            int r = tid >> 7, e = tid & 127;
            int h = e >> 5, d = e & 31;
            float acc = 0.0f;
            #pragma unroll
            for (int ss = 0; ss < Rdim; ++ss) acc += cps[h][r][ss] * vc[ss][h * CV + d];
            ctx_s[r][e] = acc;
        }
        __syncthreads();

        // K: cs masked update (all threads) + h_comm & hs masked update (192 threads)
        {
            int r = tid >> 7, j = tid & 127;
            if (mk[r] > 0.5f) cs[r][j] = cn[r][j];
        }
        if (tid < 192) {
            int r = tid / 32, c4 = tid % 32;
            int col = c4 * 4;
            if (mk[r] > 0.5f) {
                const float* wo = Wout_c + (r * Hdim) * Hdim + col;
                float4 acc = make_float4(0.f, 0.f, 0.f, 0.f);
                #pragma unroll 4
                for (int e = 0; e < Hdim; ++e) {
                    float ce = ctx_s[r][e];
                    float4 w = *(const float4*)(wo + e * Hdim);
                    acc.x += ce * w.x; acc.y += ce * w.y;
                    acc.z += ce * w.z; acc.w += ce * w.w;
                }
                hs[r][col + 0] = acc.x + hn[r][col + 0];
                hs[r][col + 1] = acc.y + hn[r][col + 1];
                hs[r][col + 2] = acc.z + hn[r][col + 2];
                hs[r][col + 3] = acc.w + hn[r][col + 3];
            }
            // inactive rows: hs already holds h_old (decayed)
        }
        __syncthreads();
    }

    // Head: out[b] = (concat(hs, statics) @ W1 + b1) @ W2 + b2
    if (tid < 64) {
        float a = b1[tid];
        const float* hsf = &hs[0][0];
        #pragma unroll 4
        for (int i = 0; i < Rdim * Hdim; ++i) a += hsf[i] * W1[i * 64 + tid];
        #pragma unroll
        for (int i = 0; i < Sdim; ++i) a += statics[b * Sdim + i] * W1[(Rdim * Hdim + i) * 64 + tid];
        float pv = a * W2[tid];
        #pragma unroll
        for (int off = 32; off > 0; off >>= 1) pv += __shfl_xor(pv, off);
        if (tid == 0) out[b] = pv + b2[0];
    }
}

extern "C" void kernel_launch(void* const* d_in, const int* in_sizes, int n_in,
                              void* d_out, int out_size, void* d_ws, size_t ws_size,
                              hipStream_t stream) {
    const float* x       = (const float*)d_in[0];
    const float* statics = (const float*)d_in[1];
    const float* mask    = (const float*)d_in[2];
    const float* delta   = (const float*)d_in[3];
    const float* xlast   = (const float*)d_in[4];
    const float* xmean   = (const float*)d_in[5];
    const float* h0      = (const float*)d_in[6];
    const float* c0      = (const float*)d_in[7];
    const float* Wgx     = (const float*)d_in[8];
    const float* bgx     = (const float*)d_in[9];
    const float* Wgh     = (const float*)d_in[10];
    const float* bgh     = (const float*)d_in[11];
    const float* Wk_in   = (const float*)d_in[12];
    const float* bk_in   = (const float*)d_in[13];
    const float* Wv_in   = (const float*)d_in[14];
    const float* bv_in   = (const float*)d_in[15];
    const float* Wq_in   = (const float*)d_in[16];
    const float* Wx_rnn  = (const float*)d_in[17];
    const float* Wh_rnn  = (const float*)d_in[18];
    const float* b_rnn   = (const float*)d_in[19];
    const float* Wq_c    = (const float*)d_in[20];
    const float* Wk_c    = (const float*)d_in[21];
    const float* Wv_c    = (const float*)d_in[22];
    const float* Wout_c  = (const float*)d_in[23];
    const float* W1      = (const float*)d_in[24];
    const float* b1      = (const float*)d_in[25];
    const float* W2      = (const float*)d_in[26];
    const float* b2      = (const float*)d_in[27];

    float* ws  = (float*)d_ws;
    float* ghG = ws;                                   // B*T*H
    float* kG  = ghG + (size_t)Bdim * Tdim * Hdim;     // B*T*DK
    float* vG  = kG  + (size_t)Bdim * Tdim * DK;       // B*T*DV

    k_pre<<<dim3(Bdim * Tdim), dim3(128), 0, stream>>>(
        x, mask, delta, xlast, xmean, Wgx, bgx, Wgh, bgh,
        Wk_in, bk_in, Wv_in, bv_in, ghG, kG, vG);

    k_seq<<<dim3(Bdim), dim3(768), 0, stream>>>(
        statics, h0, c0, bk_in, bv_in, Wq_in, Wx_rnn, Wh_rnn, b_rnn,
        Wq_c, Wk_c, Wv_c, Wout_c, W1, b1, W2, b2, ghG, kG, vG, (float*)d_out);
}

// Round 2
// 3009.737 us; speedup vs baseline: 1.6728x; 1.6728x over previous
//
#include <hip/hip_runtime.h>
#include <hip/hip_bf16.h>
#include <math.h>

#define Bdim 128
#define Tdim 96
#define Fdim 64
#define Sdim 16
#define Rdim 6
#define KACT 4
#define Hdim 128
#define DK 64
#define DV 128
#define HC 4
#define CK 32
#define CV 32

__device__ __forceinline__ float sigmoidf_(float x) { return 1.0f / (1.0f + expf(-x)); }

// ---------------- Kernel 1: precompute gamma_h, k, v for all (b,t) ----------------
__global__ __launch_bounds__(128) void k_pre(
    const float* __restrict__ x, const float* __restrict__ mask,
    const float* __restrict__ delta, const float* __restrict__ xlast,
    const float* __restrict__ xmean,
    const float* __restrict__ Wgx, const float* __restrict__ bgx,
    const float* __restrict__ Wgh, const float* __restrict__ bgh,
    const float* __restrict__ Wk, const float* __restrict__ bk,
    const float* __restrict__ Wv, const float* __restrict__ bv,
    float* __restrict__ ghO, float* __restrict__ kO, float* __restrict__ vO)
{
    const int bt = blockIdx.x;
    const int b = bt / Tdim, t = bt % Tdim;
    const int tid = threadIdx.x;
    __shared__ float d_s[Fdim], xh_s[Fdim];
    const int base = (b * Tdim + t) * Fdim;

    if (tid < Fdim) d_s[tid] = delta[base + tid];
    __syncthreads();

    if (tid < Fdim) {
        float z = bgx[tid];
        #pragma unroll 8
        for (int i = 0; i < Fdim; ++i) z += d_s[i] * Wgx[i * Fdim + tid];
        float gx = expf(-fmaxf(z, 0.0f));
        float m = mask[base + tid], xv = x[base + tid];
        float xl = xlast[base + tid], xm = xmean[b * Fdim + tid];
        xh_s[tid] = m * xv + (1.0f - m) * (gx * xl + (1.0f - gx) * xm);
    }
    {   // gamma_h: 128 outputs, all threads
        float z = bgh[tid];
        #pragma unroll 8
        for (int i = 0; i < Fdim; ++i) z += d_s[i] * Wgh[i * Hdim + tid];
        ghO[(b * Tdim + t) * Hdim + tid] = expf(-fmaxf(z, 0.0f));
    }
    __syncthreads();

    if (tid < DK) {
        float z = bk[tid];
        #pragma unroll 8
        for (int j = 0; j < Fdim; ++j) z += xh_s[j] * Wk[j * DK + tid];
        kO[(b * Tdim + t) * DK + tid] = z;
    }
    {
        float z = bv[tid];
        #pragma unroll 8
        for (int j = 0; j < Fdim; ++j) z += xh_s[j] * Wv[j * DV + tid];
        vO[(b * Tdim + t) * DV + tid] = z;
    }
}

// ---------------- Kernel 1b: BX[r,c] = bv @ Wx_rnn[r]  (tiny, runs once) ----------------
__global__ __launch_bounds__(256) void k_bx(
    const float* __restrict__ bv, const float* __restrict__ Wx_rnn,
    float* __restrict__ BX)
{
    int c = blockIdx.x * 256 + threadIdx.x;   // 0 .. R*512-1
    if (c >= Rdim * 512) return;
    int r = c >> 9, cc = c & 511;
    float acc = 0.0f;
    #pragma unroll 4
    for (int d = 0; d < DV; ++d)
        acc += bv[d] * Wx_rnn[((size_t)r * DV + d) * 512 + cc];
    BX[c] = acc;
}

// ---------------- Kernel 1c: VX[b,t,r,c] = v[b,t,:] @ Wx_rnn[r][:,c] ----------------
#define VX_BT 32
__global__ __launch_bounds__(256) void k_vx(
    const float* __restrict__ vG, const float* __restrict__ Wx_rnn,
    float* __restrict__ VX)
{
    const int bt0 = blockIdx.x * VX_BT;
    const int r = blockIdx.y;
    const int c = blockIdx.z * 128 + (threadIdx.x & 127);
    const int half = threadIdx.x >> 7;   // 0 or 1 -> which 16 bt's
    __shared__ float vv_s[VX_BT][DV];

    for (int i = threadIdx.x; i < VX_BT * DV; i += 256)
        vv_s[i >> 7][i & 127] = vG[(size_t)(bt0 + (i >> 7)) * DV + (i & 127)];
    __syncthreads();

    float acc[16];
    #pragma unroll
    for (int i = 0; i < 16; ++i) acc[i] = 0.0f;

    const float* wp = Wx_rnn + ((size_t)r * DV) * 512 + c;
    const int btb = half * 16;
    #pragma unroll 4
    for (int d = 0; d < DV; ++d) {
        float w = wp[(size_t)d * 512];
        #pragma unroll
        for (int i = 0; i < 16; ++i) acc[i] += vv_s[btb + i][d] * w;
    }
    #pragma unroll
    for (int i = 0; i < 16; ++i)
        VX[((size_t)(bt0 + btb + i) * Rdim + r) * 512 + c] = acc[i];
}

// ---------------- Kernel 2: the sequential scan, one block per batch element ----------------
__global__ __launch_bounds__(768) void k_seq(
    const float* __restrict__ statics,
    const float* __restrict__ h0, const float* __restrict__ c0,
    const float* __restrict__ bk_in, const float* __restrict__ bv_in,
    const float* __restrict__ Wq_in,
    const float* __restrict__ Wx_rnn, const float* __restrict__ Wh_rnn,
    const float* __restrict__ b_rnn,
    const float* __restrict__ Wq_c, const float* __restrict__ Wk_c,
    const float* __restrict__ Wv_c, const float* __restrict__ Wout_c,
    const float* __restrict__ W1, const float* __restrict__ b1,
    const float* __restrict__ W2, const float* __restrict__ b2,
    const float* __restrict__ ghG, const float* __restrict__ kG, const float* __restrict__ vG,
    const float* __restrict__ VX, const float* __restrict__ BX, const int use_vx,
    float* __restrict__ out)
{
    const int b = blockIdx.x;
    const int tid = threadIdx.x;
    const int wave = tid >> 6, lane = tid & 63;

    __shared__ float hs[Rdim][Hdim], cs[Rdim][Hdim], hn[Rdim][Hdim], cn[Rdim][Hdim];
    __shared__ float rim[Rdim][DV];
    __shared__ float pre_s[Rdim][4 * Hdim];
    __shared__ float qc[Rdim][Hdim], kc[Rdim][Hdim], vc[Rdim][Hdim], ctx_s[Rdim][Hdim];
    __shared__ float gh_s[Hdim], kk[DK], vv[DV], bk_s[DK], bv_s[DV];
    __shared__ float s0[Rdim], s1[Rdim], p0[Rdim], p1[Rdim], mk[Rdim];
    __shared__ float scs[HC][Rdim][Rdim], cps[HC][Rdim][Rdim];

    // init carry
    {
        int r = tid >> 7, j = tid & 127;
        hs[r][j] = h0[b * Rdim * Hdim + tid];
        cs[r][j] = c0[b * Rdim * Hdim + tid];
    }
    if (tid < DK) bk_s[tid] = bk_in[tid];
    if (tid < DV) bv_s[tid] = bv_in[tid];
    __syncthreads();

    for (int t = 0; t < Tdim; ++t) {
        // A1: load per-step precomputed vectors
        if (tid < Hdim) {
            gh_s[tid] = ghG[(b * Tdim + t) * Hdim + tid];
            if (!use_vx) vv[tid] = vG[(b * Tdim + t) * DV + tid];
        }
        if (tid < DK) kk[tid] = kG[(b * Tdim + t) * DK + tid];
        __syncthreads();

        // A2: decay hs (h_old == decayed hs; inactive rows simply keep it)
        {
            int r = tid >> 7, j = tid & 127;
            hs[r][j] *= gh_s[j];
        }
        __syncthreads();

        // B: q = hs @ Wq_in[r]; s0/s1 via in-wave reduction (wave r handles unit r)
        if (wave < Rdim) {
            const int r = wave, c = lane;
            const float* wq = Wq_in + r * Hdim * DK + c;
            float qv = 0.0f;
            #pragma unroll 8
            for (int h = 0; h < Hdim; ++h) qv += hs[r][h] * wq[h * DK];
            float a0 = qv * kk[c];
            float a1 = qv * bk_s[c];
            #pragma unroll
            for (int off = 32; off > 0; off >>= 1) {
                a0 += __shfl_xor(a0, off);
                a1 += __shfl_xor(a1, off);
            }
            if (lane == 0) { s0[r] = a0 * 0.125f; s1[r] = a1 * 0.125f; }
        }
        __syncthreads();

        // C: 2-way softmax probs + top-KACT mask (stable tie-break like jax top_k)
        if (tid < Rdim) {
            float m = fmaxf(s0[tid], s1[tid]);
            float e0 = expf(s0[tid] - m), e1 = expf(s1[tid] - m);
            float inv = 1.0f / (e0 + e1);
            p0[tid] = e0 * inv; p1[tid] = e1 * inv;
            int rank = 0;
            #pragma unroll
            for (int j = 0; j < Rdim; ++j)
                rank += (s0[j] > s0[tid] || (s0[j] == s0[tid] && j < tid)) ? 1 : 0;
            mk[tid] = (rank < KACT) ? 1.0f : 0.0f;
        }
        __syncthreads();

        // D: rim_in = p0*v + p1*bv   (only needed on the fallback path)
        if (!use_vx) {
            int r = tid >> 7, j = tid & 127;
            rim[r][j] = p0[r] * vv[j] + p1[r] * bv_s[j];
            __syncthreads();
        }

        // E: pre = p0*VX + p1*BX + hs@Wh + b  (Wx_rnn eliminated from the loop)
        {
            int r = tid >> 7, e4 = tid & 127;
            int c0i = e4 * 4;
            const float4* wh = (const float4*)(Wh_rnn + ((size_t)r * Hdim) * 512 + c0i);
            float4 acc = *(const float4*)(b_rnn + r * 512 + c0i);
            if (use_vx) {
                float4 vxv = *(const float4*)(VX + ((size_t)(b * Tdim + t) * Rdim + r) * 512 + c0i);
                float4 bxv = *(const float4*)(BX + r * 512 + c0i);
                float P0 = p0[r], P1 = p1[r];
                acc.x += P0 * vxv.x + P1 * bxv.x;
                acc.y += P0 * vxv.y + P1 * bxv.y;
                acc.z += P0 * vxv.z + P1 * bxv.z;
                acc.w += P0 * vxv.w + P1 * bxv.w;
                #pragma unroll 4
                for (int d = 0; d < Hdim; ++d) {
                    float hd = hs[r][d];
                    float4 w = wh[(size_t)d * 128];
                    acc.x += hd * w.x; acc.y += hd * w.y;
                    acc.z += hd * w.z; acc.w += hd * w.w;
                }
            } else {
                const float4* wx = (const float4*)(Wx_rnn + ((size_t)r * Hdim) * 512 + c0i);
                #pragma unroll 4
                for (int d = 0; d < Hdim; ++d) {
                    float rd = rim[r][d], hd = hs[r][d];
                    float4 a = wx[(size_t)d * 128];
                    float4 w = wh[(size_t)d * 128];
                    acc.x += rd * a.x + hd * w.x;
                    acc.y += rd * a.y + hd * w.y;
                    acc.z += rd * a.z + hd * w.z;
                    acc.w += rd * a.w + hd * w.w;
                }
            }
            *(float4*)&pre_s[r][c0i] = acc;
        }
        __syncthreads();

        // F: LSTM elementwise
        {
            int r = tid >> 7, j = tid & 127;
            float ig = pre_s[r][j];
            float fg = pre_s[r][Hdim + j];
            float gg = pre_s[r][2 * Hdim + j];
            float og = pre_s[r][3 * Hdim + j];
            float cnew = sigmoidf_(fg) * cs[r][j] + sigmoidf_(ig) * tanhf(gg);
            float hnew = sigmoidf_(og) * tanhf(cnew);
            cn[r][j] = cnew;
            hn[r][j] = hnew;   // h_b == h_new in forward pass
        }
        __syncthreads();

        // G: qc/kc/vc = hn @ {Wq_c,Wk_c,Wv_c}[r]; float4 over output cols
        if (tid < 576) {
            int r = tid / 96, e4 = tid % 96;
            int col = e4 * 4, matid = col >> 7, cc = col & 127;
            const float* Wm = (matid == 0 ? Wq_c : (matid == 1 ? Wk_c : Wv_c))
                              + ((size_t)r * Hdim) * Hdim + cc;
            float4 acc = make_float4(0.f, 0.f, 0.f, 0.f);
            #pragma unroll 4
            for (int d = 0; d < Hdim; ++d) {
                float hd = hn[r][d];
                float4 w = *(const float4*)(Wm + (size_t)d * Hdim);
                acc.x += hd * w.x; acc.y += hd * w.y;
                acc.z += hd * w.z; acc.w += hd * w.w;
            }
            float* dst = (matid == 0 ? &qc[r][cc] : (matid == 1 ? &kc[r][cc] : &vc[r][cc]));
            *(float4*)dst = acc;
        }
        __syncthreads();

        // H: attention scores over units (per head)
        if (tid < HC * Rdim * Rdim) {
            int h = tid / (Rdim * Rdim), rr = (tid / Rdim) % Rdim, ss = tid % Rdim;
            float acc = 0.0f;
            #pragma unroll 8
            for (int d = 0; d < CK; ++d) acc += qc[rr][h * CK + d] * kc[ss][h * CK + d];
            scs[h][rr][ss] = acc * 0.17677669529663687f;  // 1/sqrt(32)
        }
        __syncthreads();

        // I: softmax over s, times activation mask on r
        if (tid < HC * Rdim) {
            int h = tid / Rdim, rr = tid % Rdim;
            float m = scs[h][rr][0];
            #pragma unroll
            for (int ss = 1; ss < Rdim; ++ss) m = fmaxf(m, scs[h][rr][ss]);
            float e[Rdim], sum = 0.0f;
            #pragma unroll
            for (int ss = 0; ss < Rdim; ++ss) { e[ss] = expf(scs[h][rr][ss] - m); sum += e[ss]; }
            float inv = mk[rr] / sum;
            #pragma unroll
            for (int ss = 0; ss < Rdim; ++ss) cps[h][rr][ss] = e[ss] * inv;
        }
        __syncthreads();

        // J: ctx = cprobs @ vc
        {
            int r = tid >> 7, e = tid & 127;
            int h = e >> 5, d = e & 31;
            float acc = 0.0f;
            #pragma unroll
            for (int ss = 0; ss < Rdim; ++ss) acc += cps[h][r][ss] * vc[ss][h * CV + d];
            ctx_s[r][e] = acc;
        }
        __syncthreads();

        // K: cs masked update (all threads) + h_comm & hs masked update (192 threads)
        {
            int r = tid >> 7, j = tid & 127;
            if (mk[r] > 0.5f) cs[r][j] = cn[r][j];
        }
        if (tid < 192) {
            int r = tid / 32, c4 = tid % 32;
            int col = c4 * 4;
            if (mk[r] > 0.5f) {
                const float* wo = Wout_c + ((size_t)r * Hdim) * Hdim + col;
                float4 acc = make_float4(0.f, 0.f, 0.f, 0.f);
                #pragma unroll 4
                for (int e = 0; e < Hdim; ++e) {
                    float ce = ctx_s[r][e];
                    float4 w = *(const float4*)(wo + (size_t)e * Hdim);
                    acc.x += ce * w.x; acc.y += ce * w.y;
                    acc.z += ce * w.z; acc.w += ce * w.w;
                }
                hs[r][col + 0] = acc.x + hn[r][col + 0];
                hs[r][col + 1] = acc.y + hn[r][col + 1];
                hs[r][col + 2] = acc.z + hn[r][col + 2];
                hs[r][col + 3] = acc.w + hn[r][col + 3];
            }
            // inactive rows: hs already holds h_old (decayed)
        }
        __syncthreads();
    }

    // Head: out[b] = (concat(hs, statics) @ W1 + b1) @ W2 + b2
    if (tid < 64) {
        float a = b1[tid];
        const float* hsf = &hs[0][0];
        #pragma unroll 4
        for (int i = 0; i < Rdim * Hdim; ++i) a += hsf[i] * W1[i * 64 + tid];
        #pragma unroll
        for (int i = 0; i < Sdim; ++i) a += statics[b * Sdim + i] * W1[(Rdim * Hdim + i) * 64 + tid];
        float pv = a * W2[tid];
        #pragma unroll
        for (int off = 32; off > 0; off >>= 1) pv += __shfl_xor(pv, off);
        if (tid == 0) out[b] = pv + b2[0];
    }
}

extern "C" void kernel_launch(void* const* d_in, const int* in_sizes, int n_in,
                              void* d_out, int out_size, void* d_ws, size_t ws_size,
                              hipStream_t stream) {
    const float* x       = (const float*)d_in[0];
    const float* statics = (const float*)d_in[1];
    const float* mask    = (const float*)d_in[2];
    const float* delta   = (const float*)d_in[3];
    const float* xlast   = (const float*)d_in[4];
    const float* xmean   = (const float*)d_in[5];
    const float* h0      = (const float*)d_in[6];
    const float* c0      = (const float*)d_in[7];
    const float* Wgx     = (const float*)d_in[8];
    const float* bgx     = (const float*)d_in[9];
    const float* Wgh     = (const float*)d_in[10];
    const float* bgh     = (const float*)d_in[11];
    const float* Wk_in   = (const float*)d_in[12];
    const float* bk_in   = (const float*)d_in[13];
    const float* Wv_in   = (const float*)d_in[14];
    const float* bv_in   = (const float*)d_in[15];
    const float* Wq_in   = (const float*)d_in[16];
    const float* Wx_rnn  = (const float*)d_in[17];
    const float* Wh_rnn  = (const float*)d_in[18];
    const float* b_rnn   = (const float*)d_in[19];
    const float* Wq_c    = (const float*)d_in[20];
    const float* Wk_c    = (const float*)d_in[21];
    const float* Wv_c    = (const float*)d_in[22];
    const float* Wout_c  = (const float*)d_in[23];
    const float* W1      = (const float*)d_in[24];
    const float* b1      = (const float*)d_in[25];
    const float* W2      = (const float*)d_in[26];
    const float* b2      = (const float*)d_in[27];

    const size_t nGh = (size_t)Bdim * Tdim * Hdim;
    const size_t nK  = (size_t)Bdim * Tdim * DK;
    const size_t nV  = (size_t)Bdim * Tdim * DV;
    const size_t nBX = (size_t)Rdim * 512;
    const size_t nVX = (size_t)Bdim * Tdim * Rdim * 512;

    float* ws  = (float*)d_ws;
    float* ghG = ws;
    float* kG  = ghG + nGh;
    float* vG  = kG + nK;
    float* BX  = vG + nV;
    float* VX  = BX + nBX;

    const int use_vx = (ws_size >= (nGh + nK + nV + nBX + nVX) * sizeof(float)) ? 1 : 0;

    k_pre<<<dim3(Bdim * Tdim), dim3(128), 0, stream>>>(
        x, mask, delta, xlast, xmean, Wgx, bgx, Wgh, bgh,
        Wk_in, bk_in, Wv_in, bv_in, ghG, kG, vG);

    if (use_vx) {
        k_bx<<<dim3((Rdim * 512 + 255) / 256), dim3(256), 0, stream>>>(bv_in, Wx_rnn, BX);
        k_vx<<<dim3(Bdim * Tdim / VX_BT, Rdim, 4), dim3(256), 0, stream>>>(vG, Wx_rnn, VX);
    }

    k_seq<<<dim3(Bdim), dim3(768), 0, stream>>>(
        statics, h0, c0, bk_in, bv_in, Wq_in, Wx_rnn, Wh_rnn, b_rnn,
        Wq_c, Wk_c, Wv_c, Wout_c, W1, b1, W2, b2, ghG, kG, vG,
        use_vx ? VX : nullptr, use_vx ? BX : nullptr, use_vx, (float*)d_out);
}